// Round 8
// baseline (1418.293 us; speedup 1.0000x reference)
//
#include <hip/hip_runtime.h>

// ---------------- problem constants ----------------
constexpr int N_   = 512;
constexpr int PIX  = 1024;    // 32*32
constexpr int L_   = 1024;
constexpr int F_   = 32768;   // 32*32*32
constexpr int H_   = 512;
constexpr float IC_ = 1.0f / (float)(512 * 1024);   // 1/(N*PIX), BN count

__device__ __forceinline__ float lrelu(float t) { return t >= 0.f ? t : 0.01f * t; }

using frag  = __attribute__((ext_vector_type(8))) short;   // 8 bf16 (4 VGPRs)
using f32x4 = __attribute__((ext_vector_type(4))) float;   // MFMA accum
using s4    = __attribute__((ext_vector_type(4))) short;   // ds_write_b64 pack

// Non-draining barrier: orders LDS (lgkmcnt) but lets register-destined
// global loads stay in flight across the barrier.
#define BAR() do {                                              \
    asm volatile("s_waitcnt lgkmcnt(0)" ::: "memory");          \
    __builtin_amdgcn_s_barrier();                               \
    asm volatile("" ::: "memory");                              \
} while (0)

// split v = hi + lo, both bf16 (truncation; lo captures the tail exactly,
// dropped lo*lo term ~2^-16 relative)
__device__ __forceinline__ void split_bf16(float v, short& hi, short& lo) {
    const unsigned b = __float_as_uint(v);
    hi = (short)(b >> 16);
    const float hf = __uint_as_float(b & 0xFFFF0000u);
    lo = (short)(__float_as_uint(v - hf) >> 16);
}

// two ds_read_b64 -> one 8-bf16 fragment (stride-72B LDS rows can't align b128)
__device__ __forceinline__ frag ld2(const short* p) {
    union { frag f; struct { unsigned long long a, b; } u; } x;
    x.u.a = *(const unsigned long long*)(p);
    x.u.b = *(const unsigned long long*)(p + 4);
    return x.f;
}

// async 16-B global -> LDS (wave-uniform LDS base + lane*16; per-lane gsrc)
__device__ __forceinline__ void gll16(const float* g, float* l) {
    __builtin_amdgcn_global_load_lds(
        (const __attribute__((address_space(1))) void*)g,
        (__attribute__((address_space(3))) void*)l, 16, 0, 0);
}

// ======== weight pre-split: OIHW fp32 -> fragment-ordered bf16 hi/lo ========
// All 6 big-conv layers in ONE launch: grid (72, 6), layer = blockIdx.y.
__global__ __launch_bounds__(256) void wsplit6_kernel(
    const float* __restrict__ w0, const float* __restrict__ w1,
    const float* __restrict__ w2, const float* __restrict__ w3,
    const float* __restrict__ w4, const float* __restrict__ w5,
    short* __restrict__ hi, short* __restrict__ lo)
{
    const int layer = blockIdx.y;
    const float* W = layer == 0 ? w0 : layer == 1 ? w1 : layer == 2 ? w2 :
                     layer == 3 ? w3 : layer == 4 ? w4 : w5;
    const int CIN  = (layer == 1 || layer == 3) ? 64 : 32;
    const int NCOT = (layer == 1 || layer == 3) ? 2 : 4;
    const int idx = blockIdx.x * 256 + threadIdx.x;       // 72*256 = 18432 exact
    const int j    = idx & 7;
    const int lane = (idx >> 3) & 63;
    const int q    = lane >> 4, lm = lane & 15;
    const int blk  = idx >> 9;
    const int cot  = blk % NCOT;
    const int rest = blk / NCOT;
    const int pos  = rest % 9;
    const int cc   = rest / 9;
    const int co = cot * 16 + lm;
    const int ci = cc * 32 + q * 8 + j;
    short h, l;
    split_bf16(W[((size_t)co * CIN + ci) * 9 + pos], h, l);
    hi[layer * 18432 + idx] = h;
    lo[layer * 18432 + idx] = l;
}

// ======== conv 3x3 SAME via implicit-GEMM MFMA (split-bf16, 3-pass) =========
// R7-proven: 8-wave (512 thr) blocks, cot-split. Block = one image, 8 output
// rows, ALL Cout. Wave (pgrp = wv&3, cotg = wv>>2) owns ptiles pgrp*4..+3
// x cots cotg*NCOT2..+NCOT2-1.
template<int CIN, int COUT, bool BN_IN>
__global__ __launch_bounds__(512) void conv_mfma(
    const float* __restrict__ in, const short* __restrict__ wh,
    const short* __restrict__ wl, const float* __restrict__ bias,
    float* __restrict__ out, const float* __restrict__ stats_in,
    float* __restrict__ stats_out)
{
    constexpr int NCOT  = COUT / 16;
    constexpr int NCOT2 = NCOT / 2;       // cots per wave
    constexpr int NCH   = CIN / 32;
    constexpr int STR  = 36;              // shorts per staged pixel
    constexpr int PLsh = 340 * STR;       // plane: 10 rows x 34 cols
    __shared__ __align__(16) short hiL[PLsh];
    __shared__ __align__(16) short loL[PLsh];       // ~48 KB
    __shared__ float red[2 * COUT];
    __shared__ float bnm[64], bni[64];
    const int tid  = threadIdx.x;
    const int n    = blockIdx.x >> 2;
    const int y0   = (blockIdx.x & 3) << 3;
    const int lane = tid & 63;
    const int wv   = tid >> 6;            // 0..7
    const int pgrp = wv & 3;              // ptile quarter
    const int cotg = wv >> 2;             // cot half
    const int lm   = lane & 15;
    const int q    = lane >> 4;

    if (tid < 2 * COUT) red[tid] = 0.f;
    if (BN_IN && tid < CIN) {
        const float m  = stats_in[tid] * IC_;
        const float qq = stats_in[CIN + tid] * IC_;
        bnm[tid] = m;
        bni[tid] = rsqrtf(qq - m * m + 1e-5f);
    }
    __syncthreads();

    f32x4 acc[NCOT2][4];
#pragma unroll
    for (int t = 0; t < NCOT2; ++t)
#pragma unroll
        for (int pt = 0; pt < 4; ++pt) acc[t][pt] = {0.f, 0.f, 0.f, 0.f};

    // staging coords: 340 staged px, one per thread (tid < 340)
    const int rs0 = tid / 34, cs0 = tid % 34;
    const int gr0 = y0 - 1 + rs0, gc0 = cs0 - 1;
    const bool act = tid < 340;
    const bool ok0 = act && ((unsigned)gr0 < 32u) && ((unsigned)gc0 < 32u);
    const int  po0 = gr0 * 32 + gc0;

    const float* inb = in + ((size_t)n * CIN << 10);

    // weight fragment double-buffer (static register sets — no runtime index)
    frag ahA[NCOT2], alA[NCOT2], ahB[NCOT2], alB[NCOT2];

    auto LDW = [&](frag (&dh)[NCOT2], frag (&dl)[NCOT2], int posAbs) {
#pragma unroll
        for (int t = 0; t < NCOT2; ++t) {
            const int cot = cotg * NCOT2 + t;
            const size_t wb = (size_t)((posAbs * NCOT + cot) * 512 + lane * 8);
            dh[t] = *(const frag*)&wh[wb];
            dl[t] = *(const frag*)&wl[wb];
        }
    };

    auto COMPUTE = [&](int pos, frag (&fh)[NCOT2], frag (&fl)[NCOT2]) {
        const int ky = pos / 3, kx = pos - ky * 3;
        __builtin_amdgcn_s_setprio(1);
#pragma unroll
        for (int pt = 0; pt < 4; ++pt) {
            const int ptile = pgrp * 4 + pt;
            const int row = ptile >> 1;
            const int col = ((ptile & 1) << 4) + lm;
            const int loff = ((row + ky) * 34 + col + kx) * STR + q * 8;
            const frag bh = ld2(&hiL[loff]);
            const frag bl = ld2(&loL[loff]);
#pragma unroll
            for (int t = 0; t < NCOT2; ++t) {
                acc[t][pt] = __builtin_amdgcn_mfma_f32_16x16x32_bf16(
                    fh[t], bh, acc[t][pt], 0, 0, 0);
                acc[t][pt] = __builtin_amdgcn_mfma_f32_16x16x32_bf16(
                    fh[t], bl, acc[t][pt], 0, 0, 0);
                acc[t][pt] = __builtin_amdgcn_mfma_f32_16x16x32_bf16(
                    fl[t], bh, acc[t][pt], 0, 0, 0);
            }
        }
        __builtin_amdgcn_s_setprio(0);
    };

#pragma unroll 1
    for (int cc = 0; cc < NCH; ++cc) {
        if (cc) BAR();                    // previous chunk's reads done

        // prefetch pos-0 weights of this chunk; flies under the staging phase
        LDW(ahA, alA, cc * 9 + 0);

        // ---- staging: one px per thread, 16-channel batches ----
#pragma unroll 1
        for (int cb = 0; cb < 32; cb += 16) {
            float v0r[16];
#pragma unroll
            for (int u = 0; u < 16; ++u) {
                const int cg = cc * 32 + cb + u;
                v0r[u] = ok0 ? inb[((size_t)cg << 10) + po0] : 0.f;
            }
            if (act) {
#pragma unroll
                for (int u4 = 0; u4 < 16; u4 += 4) {
                    s4 h0v, l0v;
#pragma unroll
                    for (int e = 0; e < 4; ++e) {
                        const int ci = cb + u4 + e;
                        const int cg = cc * 32 + ci;
                        float v0 = v0r[u4 + e];
                        if (BN_IN && ok0) v0 = lrelu((v0 - bnm[cg]) * bni[cg]);
                        short h, l;
                        split_bf16(v0, h, l);
                        h0v[e] = h; l0v[e] = l;
                    }
                    *(s4*)&hiL[tid * STR + cb + u4] = h0v;
                    *(s4*)&loL[tid * STR + cb + u4] = l0v;
                }
            }
        }
        BAR();

        // ---- 9 positions, weights double-buffered (A holds pos, B pos+1) ---
#pragma unroll 1
        for (int pos = 0; pos < 8; pos += 2) {
            LDW(ahB, alB, cc * 9 + pos + 1);   // prefetch pos+1
            COMPUTE(pos, ahA, alA);            // consume pos (already landed)
            LDW(ahA, alA, cc * 9 + pos + 2);   // prefetch pos+2 (max 8)
            COMPUTE(pos + 1, ahB, alB);        // consume pos+1
        }
        COMPUTE(8, ahA, alA);                  // tail: pos 8
    }

    // ---- epilogue: bias, store raw, per-channel stats ----
    // C/D: col(n=px)=lane&15, row(m=co within tile)=q*4+reg
    float* ob = out + ((size_t)n * COUT << 10);
#pragma unroll
    for (int t = 0; t < NCOT2; ++t) {
#pragma unroll
        for (int r = 0; r < 4; ++r) {
            const int co = (cotg * NCOT2 + t) * 16 + q * 4 + r;
            const float b = bias[co];
            float s = 0.f, sq = 0.f;
#pragma unroll
            for (int pt = 0; pt < 4; ++pt) {
                const int ptile = pgrp * 4 + pt;
                const float v = acc[t][pt][r] + b;
                ob[((size_t)co << 10) + (y0 << 5) + (ptile << 4) + lm] = v;
                s += v; sq += v * v;
            }
#pragma unroll
            for (int off = 8; off > 0; off >>= 1) {
                s  += __shfl_down(s, off, 64);
                sq += __shfl_down(sq, off, 64);
            }
            if (lm == 0) {
                atomicAdd(&red[co], s);
                atomicAdd(&red[COUT + co], sq);
            }
        }
    }
    __syncthreads();
    if (tid < 2 * COUT) atomicAdd(&stats_out[tid], red[tid]);
}

// ================= conv 3x3 VALU — conv1 & dec-conv3 only ===
template<int CIN, int COPB, bool BN_IN>
__global__ __launch_bounds__(256) void conv3x3(
    const float* __restrict__ in, const float* __restrict__ w,
    const float* __restrict__ bias, float* __restrict__ out,
    const float* __restrict__ stats_in, float* __restrict__ stats_out,
    int Cout)
{
    constexpr int CT = (CIN < 4) ? CIN : 4;
    __shared__ float tile[CT * PIX];
    __shared__ float red[2 * COPB];
    const int groups = Cout / COPB;
    const int n   = blockIdx.x / groups;
    const int co0 = (blockIdx.x % groups) * COPB;
    const int tid = threadIdx.x;
    const int x   = tid & 31;
    const int y0  = (tid >> 5) * 4;

    float acc[COPB][4];
#pragma unroll
    for (int c = 0; c < COPB; ++c)
#pragma unroll
        for (int j = 0; j < 4; ++j) acc[c][j] = 0.f;

    const float* inbase = in + (size_t)n * CIN * PIX;

#pragma unroll 1
    for (int s0 = 0; s0 < CIN; s0 += CT) {
        __syncthreads();
#pragma unroll
        for (int s = 0; s < CT; ++s) {
            float4 v = ((const float4*)(inbase + (size_t)(s0 + s) * PIX))[tid];
            if (BN_IN) {
                const int c = s0 + s;
                const float m   = stats_in[c] * IC_;
                const float q   = stats_in[CIN + c] * IC_;
                const float inv = rsqrtf(q - m * m + 1e-5f);
                v.x = lrelu((v.x - m) * inv);
                v.y = lrelu((v.y - m) * inv);
                v.z = lrelu((v.z - m) * inv);
                v.w = lrelu((v.w - m) * inv);
            }
            ((float4*)tile)[s * 256 + tid] = v;
        }
        __syncthreads();
#pragma unroll 2
        for (int s = 0; s < CT; ++s) {
            const int ci = s0 + s;
            const float* tp = tile + s * PIX;
            float r[6][3];
#pragma unroll
            for (int ry = 0; ry < 6; ++ry) {
                const int yy = y0 + ry - 1;
                const bool yok = (unsigned)yy < 32u;
#pragma unroll
                for (int cx = 0; cx < 3; ++cx) {
                    const int xx = x + cx - 1;
                    const bool ok = yok && ((unsigned)xx < 32u);
                    r[ry][cx] = ok ? tp[yy * 32 + xx] : 0.f;
                }
            }
#pragma unroll
            for (int c = 0; c < COPB; ++c) {
                const float* wp = w + ((size_t)(co0 + c) * CIN + ci) * 9;
#pragma unroll
                for (int ky = 0; ky < 3; ++ky)
#pragma unroll
                    for (int kx = 0; kx < 3; ++kx) {
                        const float wv = wp[ky * 3 + kx];
#pragma unroll
                        for (int j = 0; j < 4; ++j)
                            acc[c][j] += r[ky + j][kx] * wv;
                    }
            }
        }
    }

    if (tid < 2 * COPB) red[tid] = 0.f;
    __syncthreads();
#pragma unroll
    for (int c = 0; c < COPB; ++c) {
        const float b = bias[co0 + c];
        float* ob = out + (((size_t)n * Cout + co0 + c) << 10);
        float s = 0.f, q = 0.f;
#pragma unroll
        for (int j = 0; j < 4; ++j) {
            const float v = acc[c][j] + b;
            ob[(y0 + j) * 32 + x] = v;
            s += v; q += v * v;
        }
#pragma unroll
        for (int off = 32; off > 0; off >>= 1) {
            s += __shfl_down(s, off, 64);
            q += __shfl_down(q, off, 64);
        }
        if ((tid & 63) == 0) {
            atomicAdd(&red[c], s);
            atomicAdd(&red[COPB + c], q);
        }
    }
    __syncthreads();
    if (tid < COPB)
        atomicAdd(&stats_out[co0 + tid], red[tid]);
    else if (tid < 2 * COPB)
        atomicAdd(&stats_out[Cout + co0 + tid - COPB], red[tid]);
}

// ======== split-bf16 MFMA GEMM v3: async global_load_lds staging ========
// fp32 A/B tiles land in LDS via global_load_lds (no VGPR round-trip;
// ~32 KB/block in flight during MFMA — Little's-law fix for the 2.4 TB/s
// plateau). split-bf16 conversion + MODE transform move to the consumer,
// in-register per fragment. Bank-conflict fix per G21: linear LDS dest +
// inverse piece-swizzled GLOBAL source (piece = (l&7)^(l>>3)) + swizzled
// ds_read (piece = 2q^(row&7)) — row-major [128][32] fp32 would otherwise
// be a 16-way conflict. Schedule: ISSUE(s+1) into the buffer freed at the
// end of step s-1, then MMA(s), vmcnt(0), BAR — race-free double buffer.
// MODE 0: raw A. MODE 1: BN+lrelu(A), kchunk=2048 -> block-uniform stats.
// MODE 2: bias+lrelu(A), bias indexed by k (per-head pointer).
template<int MODE>
__global__ __launch_bounds__(256) void gemm_mfma(
    const float* __restrict__ A0, const float* __restrict__ A1,
    const float* __restrict__ B0, const float* __restrict__ B1,
    float* __restrict__ C0, float* __restrict__ C1,
    int K, int Nh, int kchunk, int xph,
    const float* __restrict__ bnstats, int Cin,
    const float* __restrict__ ba0, const float* __restrict__ ba1)
{
    __shared__ __align__(16) float AfL[2 * 4096];   // 2 bufs x 128 rows x 32 k
    __shared__ __align__(16) float BfL[2 * 4096];   // 64 KB total
    const int tid  = threadIdx.x;
    const int head = blockIdx.x / xph;
    const int n0   = (blockIdx.x % xph) * 128;
    const int m0   = blockIdx.y * 128;
    const float* A = head ? A1 : A0;
    const float* B = head ? B1 : B0;
    float*       C = head ? C1 : C0;
    const float* BA = head ? ba1 : ba0;
    const int k0 = blockIdx.z * kchunk;

    const int lane = tid & 63;
    const int wv   = tid >> 6;
    const int wm   = wv & 1;
    const int wn   = wv >> 1;
    const int lm   = lane & 15;
    const int q    = lane >> 4;

    // producer lane coords: physical piece (l&7) of row 8c+(l>>3) holds
    // logical k-piece (l&7)^(row&7); row&7 == l>>3 within a chunk.
    const int lrow = lane >> 3;                 // 0..7
    const int lpk  = ((lane & 7) ^ lrow) << 2;  // k offset (floats)

    // block-uniform BN (MODE 1): kchunk=2048 -> channels c0, c0+1
    float bnm0 = 0.f, bni0 = 1.f, bnm1 = 0.f, bni1 = 1.f;
    if (MODE == 1) {
        const int c0 = k0 >> 10;
        bnm0 = bnstats[c0] * IC_;
        const float q0 = bnstats[Cin + c0] * IC_;
        bni0 = rsqrtf(q0 - bnm0 * bnm0 + 1e-5f);
        const int c1 = (c0 + 1 < Cin) ? c0 + 1 : c0;
        bnm1 = bnstats[c1] * IC_;
        const float q1 = bnstats[Cin + c1] * IC_;
        bni1 = rsqrtf(q1 - bnm1 * bnm1 + 1e-5f);
    }

    f32x4 acc[4][4];
#pragma unroll
    for (int i = 0; i < 4; ++i)
#pragma unroll
        for (int j = 0; j < 4; ++j) acc[i][j] = {0.f, 0.f, 0.f, 0.f};

    // issue 8 async 16-B loads (4 A-chunks + 4 B-chunks owned by this wave)
    auto ISSUE = [&](int s, int kb) {
        float* lba = &AfL[(s & 1) << 12];
        float* lbb = &BfL[(s & 1) << 12];
#pragma unroll
        for (int j = 0; j < 4; ++j) {
            const int c = wv * 4 + j;               // chunk 0..15
            const int row = (c << 3) + lrow;        // 0..127
            gll16(A + (size_t)(m0 + row) * K + kb + lpk, lba + (c << 8));
            gll16(B + (size_t)(n0 + row) * K + kb + lpk, lbb + (c << 8));
        }
    };

    auto MMA = [&](int s, int kb) {
        const float* Ap = &AfL[(s & 1) << 12];
        const float* Bp = &BfL[(s & 1) << 12];
        float bm = 0.f, bi = 1.f;
        if (MODE == 1) {
            const int sel = s & 32;                 // step>=32 -> channel c0+1
            bm = sel ? bnm1 : bnm0;
            bi = sel ? bni1 : bni0;
        }
        float bv[8];
        if (MODE == 2) {
            const float* bp = BA + kb + q * 8;
            *(float4*)&bv[0] = ((const float4*)bp)[0];
            *(float4*)&bv[4] = ((const float4*)bp)[1];
        }
        frag fah[4], fal[4], fbh[4], fbl[4];
#pragma unroll
        for (int t = 0; t < 4; ++t) {
            const int ra = wm * 64 + t * 16 + lm;
            const int rb = wn * 64 + t * 16 + lm;
            const int ma = ra & 7, mb = rb & 7;
            float va[8], vb[8];
            *(float4*)&va[0] = *(const float4*)&Ap[ra * 32 + ((( q << 1)      ^ ma) << 2)];
            *(float4*)&va[4] = *(const float4*)&Ap[ra * 32 + ((((q << 1) | 1) ^ ma) << 2)];
            *(float4*)&vb[0] = *(const float4*)&Bp[rb * 32 + ((( q << 1)      ^ mb) << 2)];
            *(float4*)&vb[4] = *(const float4*)&Bp[rb * 32 + ((((q << 1) | 1) ^ mb) << 2)];
#pragma unroll
            for (int e = 0; e < 8; ++e) {
                float v = va[e];
                if (MODE == 1) v = lrelu((v - bm) * bi);
                if (MODE == 2) v = lrelu(v + bv[e]);
                short hh, ll;
                split_bf16(v, hh, ll);
                fah[t][e] = hh; fal[t][e] = ll;
                short h2, l2;
                split_bf16(vb[e], h2, l2);
                fbh[t][e] = h2; fbl[t][e] = l2;
            }
        }
        __builtin_amdgcn_s_setprio(1);
#pragma unroll
        for (int i = 0; i < 4; ++i)
#pragma unroll
            for (int j = 0; j < 4; ++j) {
                acc[i][j] = __builtin_amdgcn_mfma_f32_16x16x32_bf16(
                    fah[i], fbh[j], acc[i][j], 0, 0, 0);
                acc[i][j] = __builtin_amdgcn_mfma_f32_16x16x32_bf16(
                    fah[i], fbl[j], acc[i][j], 0, 0, 0);
                acc[i][j] = __builtin_amdgcn_mfma_f32_16x16x32_bf16(
                    fal[i], fbh[j], acc[i][j], 0, 0, 0);
            }
        __builtin_amdgcn_s_setprio(0);
    };

    const int T = kchunk >> 5;                      // K-steps per block

    ISSUE(0, k0);
    asm volatile("s_waitcnt vmcnt(0)" ::: "memory");
    __syncthreads();

#pragma unroll 1
    for (int s = 0; s < T; ++s) {
        // target buffer (s+1)&1 was freed by all waves at end of step s-1
        if (s + 1 < T) ISSUE(s + 1, k0 + (s + 1) * 32);
        MMA(s, k0 + s * 32);
        asm volatile("s_waitcnt vmcnt(0)" ::: "memory");  // covered by MMA
        BAR();
    }

#pragma unroll
    for (int i = 0; i < 4; ++i) {
        const int m = m0 + wm * 64 + i * 16 + q * 4;
#pragma unroll
        for (int j = 0; j < 4; ++j) {
            const int n = n0 + wn * 64 + j * 16 + lm;
            float* cp = C + (size_t)m * Nh + n;
#pragma unroll
            for (int r = 0; r < 4; ++r)
                atomicAdd(cp + (size_t)r * Nh, acc[i][j][r]);
        }
    }
}

// ================= block reduce + atomic helper =================
__device__ __forceinline__ void block_reduce_atomic(float t, float* target)
{
#pragma unroll
    for (int off = 32; off > 0; off >>= 1) t += __shfl_down(t, off, 64);
    __shared__ float lt[4];
    const int wave = threadIdx.x >> 6, lane = threadIdx.x & 63;
    if (lane == 0) lt[wave] = t;
    __syncthreads();
    if (threadIdx.x == 0) atomicAdd(target, lt[0] + lt[1] + lt[2] + lt[3]);
}

// ===== product-of-experts group posterior + kl2 (bias+lrelu fused in) =====
__global__ __launch_bounds__(256) void poe_kernel(
    const float* __restrict__ mu1, const float* __restrict__ lv1,
    const float* __restrict__ bmu, const float* __restrict__ blv,
    float* __restrict__ gmu, float* __restrict__ glv, float* __restrict__ kl)
{
    const int l = blockIdx.x * 256 + threadIdx.x;
    const float bm = bmu[l], bl = blv[l];
    float sp = 0.f, sm = 0.f;
    for (int n = 0; n < N_; ++n) {
        const float lv = lrelu(lv1[(size_t)n * L_ + l] + bl);
        const float p  = expf(-lv);
        sp += p;
        sm += lrelu(mu1[(size_t)n * L_ + l] + bm) * p;
    }
    const float gv = 1.f / sp;
    const float gm = sm * gv;
    const float gl = -logf(sp);
    gmu[l] = gm;
    glv[l] = gl;
    const float t = -0.5f * (1.f + gl) + 0.5f * (gm * gm + gv * gv);
    block_reduce_atomic(t, &kl[1]);
}

// ============ reparameterize + kl1 (bias+lrelu fused in) ============
__global__ __launch_bounds__(256) void reparam_kernel(
    const float* __restrict__ mu0, const float* __restrict__ lv0,
    const float* __restrict__ bmu, const float* __restrict__ blv,
    const float* __restrict__ eps_c, const float* __restrict__ eps_s,
    const float* __restrict__ gmu, const float* __restrict__ glv,
    float* __restrict__ zc, float* __restrict__ zs, float* __restrict__ kl)
{
    const int idx = blockIdx.x * 256 + threadIdx.x;
    const int l = idx & (L_ - 1);
    const float m  = lrelu(mu0[idx] + bmu[l]);
    const float lv = lrelu(lv0[idx] + blv[l]);
    zc[idx] = eps_c[idx] * expf(0.5f * lv) + m;
    zs[idx] = eps_s[idx] * expf(0.5f * glv[l]) + gmu[l];
    const float e = expf(lv);
    const float t = -0.5f * (1.f + lv) + 0.5f * (m * m + e * e);
    block_reduce_atomic(t, &kl[0]);
}

// ================= final: BN of decoder outputs + output + loss ============
__global__ __launch_bounds__(256) void final_kernel(
    const float* __restrict__ x, const float* __restrict__ oc,
    const float* __restrict__ os, const float* __restrict__ stC,
    const float* __restrict__ stS, const float* __restrict__ kl,
    float* __restrict__ out)
{
    const int idx = blockIdx.x * 256 + threadIdx.x;
    const float mc = stC[0] * IC_, qc = stC[1] * IC_;
    const float ivc = rsqrtf(qc - mc * mc + 1e-5f);
    const float ms = stS[0] * IC_, qs = stS[1] * IC_;
    const float ivs = rsqrtf(qs - ms * ms + 1e-5f);
    const float tc = lrelu((oc[idx] - mc) * ivc);
    const float ts = fmaxf((os[idx] - ms) * ivs, 0.f);
    const float o = tc * ts;
    const float d = expf(x[idx]) - expf(o);
    out[idx]            = -kl[0] + kl[1] + d * d;
    out[N_ * PIX + idx] = o;
}

// ================= host launch =================
extern "C" void kernel_launch(void* const* d_in, const int* in_sizes, int n_in,
                              void* d_out, int out_size, void* d_ws, size_t ws_size,
                              hipStream_t stream)
{
    const float* x        = (const float*)d_in[0];
    const float* eps_c    = (const float*)d_in[1];
    const float* eps_s    = (const float*)d_in[2];
    const float* enc_cw1  = (const float*)d_in[3];
    const float* enc_cb1  = (const float*)d_in[4];
    const float* enc_cw2  = (const float*)d_in[5];
    const float* enc_cb2  = (const float*)d_in[6];
    const float* enc_cw3  = (const float*)d_in[7];
    const float* enc_cb3  = (const float*)d_in[8];
    const float* enc_muW1 = (const float*)d_in[9];
    const float* enc_muB1 = (const float*)d_in[10];
    const float* enc_muW2 = (const float*)d_in[11];
    const float* enc_muB2 = (const float*)d_in[12];
    const float* enc_vaW1 = (const float*)d_in[13];
    const float* enc_vaB1 = (const float*)d_in[14];
    const float* enc_vaW2 = (const float*)d_in[15];
    const float* enc_vaB2 = (const float*)d_in[16];
    const float* dec_cw1  = (const float*)d_in[17];
    const float* dec_cb1  = (const float*)d_in[18];
    const float* dec_cw2  = (const float*)d_in[19];
    const float* dec_cb2  = (const float*)d_in[20];
    const float* dec_cw3  = (const float*)d_in[21];
    const float* dec_cb3  = (const float*)d_in[22];
    float* out = (float*)d_out;

    // ---- workspace layout (floats) ----
    float* ws   = (float*)d_ws;
    float* bufA = ws;                             // N*64*PIX
    float* bufB = bufA + (size_t)N_ * 64 * PIX;   // N*32*PIX
    float* h1   = bufB + (size_t)N_ * 32 * PIX;   // N*H
    float* h2   = h1 + N_ * H_;
    float* mu0  = h2 + N_ * H_;                   // N*L each below
    float* lv0  = mu0 + N_ * L_;
    float* mu1  = lv0 + N_ * L_;
    float* lv1  = mu1 + N_ * L_;
    float* zc   = lv1 + N_ * L_;
    float* zs   = zc + N_ * L_;
    float* oc   = zs + N_ * L_;
    float* os   = oc + N_ * L_;
    float* gmu  = os + N_ * L_;                   // L
    float* glv  = gmu + L_;                       // L
    float* stats = glv + L_;                      // 12 slots x 128
    float* kl   = stats + 12 * 128;               // 4 (2 used, pad to align)
    // pre-split conv weights (16-B aligned: float offset is multiple of 4)
    short* wsh  = (short*)(kl + 4);               // 6 layers x 18432 shorts (hi)
    short* wsl  = wsh + 6 * 18432;                // (lo)

    auto st  = [&](int s) { return stats + 128 * s; };
    auto whp = [&](int layer) { return wsh + layer * 18432; };
    auto wlp = [&](int layer) { return wsl + layer * 18432; };

    // stats + kl are contiguous: one memset
    hipMemsetAsync(stats, 0, (12 * 128 + 4) * sizeof(float), stream);

    // pre-split conv weights into MFMA fragment order (all 6 layers, 1 launch)
    wsplit6_kernel<<<dim3(72, 6), 256, 0, stream>>>(
        enc_cw2, enc_cw3, enc_cw2 + 64 * 32 * 9, enc_cw3 + 32 * 64 * 9,
        dec_cw2, dec_cw2 + 64 * 32 * 9, wsh, wsl);

    // ================== encoders ==================
    for (int i = 0; i < 2; ++i) {
        const float* cw1 = enc_cw1 + (size_t)i * 32 * 9;
        const float* cb1 = enc_cb1 + (size_t)i * 32;
        const float* cb2 = enc_cb2 + (size_t)i * 64;
        const float* cb3 = enc_cb3 + (size_t)i * 32;

        conv3x3<1, 16, false><<<N_ * 2, 256, 0, stream>>>(
            x, cw1, cb1, bufB, nullptr, st(i * 3 + 0), 32);
        conv_mfma<32, 64, true><<<N_ * 4, 512, 0, stream>>>(
            bufB, whp(i * 2), wlp(i * 2), cb2, bufA, st(i * 3 + 0), st(i * 3 + 1));
        conv_mfma<64, 32, true><<<N_ * 4, 512, 0, stream>>>(
            bufA, whp(i * 2 + 1), wlp(i * 2 + 1), cb3, bufB, st(i * 3 + 1), st(i * 3 + 2));
        // bufB = raw conv3 out; BN+lrelu fused into GEMM A staging

        const float* W1m = enc_muW1 + (size_t)i * H_ * F_;
        const float* B1m = enc_muB1 + (size_t)i * H_;
        const float* W2m = enc_muW2 + (size_t)i * L_ * H_;
        const float* W1v = enc_vaW1 + (size_t)i * H_ * F_;
        const float* B1v = enc_vaB1 + (size_t)i * H_;
        const float* W2v = enc_vaW2 + (size_t)i * L_ * H_;
        float* mu_i = (i == 0) ? mu0 : mu1;
        float* lv_i = (i == 0) ? lv0 : lv1;

        // h1,h2 contiguous; mu_i,lv_i contiguous: one memset each
        hipMemsetAsync(h1, 0, (size_t)2 * N_ * H_ * sizeof(float), stream);
        gemm_mfma<1><<<dim3(8, 4, 16), 256, 0, stream>>>(
            bufB, bufB, W1m, W1v, h1, h2, F_, H_, 2048, 4,
            st(i * 3 + 2), 32, nullptr, nullptr);

        // h bias+lrelu fused into W2-GEMM A-staging (MODE 2)
        hipMemsetAsync(mu_i, 0, (size_t)2 * N_ * L_ * sizeof(float), stream);
        gemm_mfma<2><<<dim3(16, 4, 4), 256, 0, stream>>>(
            h1, h2, W2m, W2v, mu_i, lv_i, H_, L_, 128, 8,
            nullptr, 0, B1m, B1v);
        // mu_i/lv_i left raw (+bias+lrelu applied by consumers below)
    }

    // ======= PoE + reparam + KL (encoder-head biases fused in) =======
    poe_kernel<<<L_ / 256, 256, 0, stream>>>(
        mu1, lv1, enc_muB2 + L_, enc_vaB2 + L_, gmu, glv, kl);
    reparam_kernel<<<(N_ * L_) / 256, 256, 0, stream>>>(
        mu0, lv0, enc_muB2, enc_vaB2, eps_c, eps_s, gmu, glv, zc, zs, kl);

    // ================== decoders ==================
    for (int i = 0; i < 2; ++i) {
        const float* cw1 = dec_cw1 + (size_t)i * 32 * 9;
        const float* cb1 = dec_cb1 + (size_t)i * 32;
        const float* cb2 = dec_cb2 + (size_t)i * 64;
        const float* cw3 = dec_cw3 + (size_t)i * 64 * 9;
        const float* cb3 = dec_cb3 + (size_t)i * 1;
        const float* zi = (i == 0) ? zc : zs;
        float* oi = (i == 0) ? oc : os;

        conv3x3<1, 16, false><<<N_ * 2, 256, 0, stream>>>(
            zi, cw1, cb1, bufB, nullptr, st(6 + i * 3 + 0), 32);
        conv_mfma<32, 64, true><<<N_ * 4, 512, 0, stream>>>(
            bufB, whp(4 + i), wlp(4 + i), cb2, bufA, st(6 + i * 3 + 0), st(6 + i * 3 + 1));
        conv3x3<64, 1, true><<<N_, 256, 0, stream>>>(
            bufA, cw3, cb3, oi, st(6 + i * 3 + 1), st(6 + i * 3 + 2), 1);
    }

    // ================== output + loss (BN of oc/os fused) ==================
    final_kernel<<<(N_ * PIX) / 256, 256, 0, stream>>>(
        x, oc, os, st(8), st(11), kl, out);
}